// Round 1
// baseline (187.060 us; speedup 1.0000x reference)
//
#include <hip/hip_runtime.h>

#define IMG_W 1024
#define IMG_H 1024
#define NBATCH 32

// One level-1 Haar quad: inputs a,b (top row), c,d (bottom row).
// Writes cA, accumulates min(|cH|,thr)+min(|cV|,thr)+min(|cD|,thr) into lsum.
__device__ __forceinline__ void haar_quad(float a, float b, float c, float d,
                                          float thr, float& cA, float& lsum) {
    float s1 = a + b, s2 = c + d;
    float d1 = a - b, d2 = c - d;
    cA = (s1 + s2) * 0.5f;
    float cH = (s1 - s2) * 0.5f;
    float cV = (d1 + d2) * 0.5f;
    float cD = (d1 - d2) * 0.5f;
    lsum += fminf(fabsf(cH), thr) + fminf(fabsf(cV), thr) + fminf(fabsf(cD), thr);
}

__global__ __launch_bounds__(256)
void WaveletSparsityLoss_34746285424743_kernel(const float* __restrict__ pred,
                                               float* __restrict__ out) {
    int tid = blockIdx.x * blockDim.x + threadIdx.x;
    // 32 batches * (128x128) 8x8-tiles = 524288 threads
    int batch = tid >> 14;         // tid / 16384
    int t     = tid & 16383;
    int tr    = t >> 7;            // tile row (0..127)
    int tc    = t & 127;           // tile col (0..127)

    const float* img = pred + (size_t)batch * (IMG_W * IMG_H);
    int r0 = tr * 8;
    int c0 = tc * 8;               // multiple of 8 floats -> 32B aligned

    const float thr1 = 50.0f / 4.0f / 255.0f;   // level_idx 3
    const float thr2 = 50.0f / 2.0f / 255.0f;   // level_idx 2
    const float thr3 = 50.0f / 255.0f;          // level_idx 1

    float l1 = 0.0f, l2 = 0.0f, l3 = 0.0f;
    float cA1[4][4];

    #pragma unroll
    for (int i = 0; i < 4; ++i) {
        const float4* rowA = reinterpret_cast<const float4*>(
            img + (size_t)(r0 + 2 * i) * IMG_W + c0);
        const float4* rowB = reinterpret_cast<const float4*>(
            img + (size_t)(r0 + 2 * i + 1) * IMG_W + c0);
        float4 a0 = rowA[0], a1 = rowA[1];
        float4 b0 = rowB[0], b1 = rowB[1];
        haar_quad(a0.x, a0.y, b0.x, b0.y, thr1, cA1[i][0], l1);
        haar_quad(a0.z, a0.w, b0.z, b0.w, thr1, cA1[i][1], l1);
        haar_quad(a1.x, a1.y, b1.x, b1.y, thr1, cA1[i][2], l1);
        haar_quad(a1.z, a1.w, b1.z, b1.w, thr1, cA1[i][3], l1);
    }

    float cA2[2][2];
    #pragma unroll
    for (int i = 0; i < 2; ++i) {
        haar_quad(cA1[2*i][0], cA1[2*i][1], cA1[2*i+1][0], cA1[2*i+1][1],
                  thr2, cA2[i][0], l2);
        haar_quad(cA1[2*i][2], cA1[2*i][3], cA1[2*i+1][2], cA1[2*i+1][3],
                  thr2, cA2[i][1], l2);
    }

    float cA3;
    haar_quad(cA2[0][0], cA2[0][1], cA2[1][0], cA2[1][1], thr3, cA3, l3);
    (void)cA3; // discarded at the last level

    // weight_s / (3 * N_s):
    const float C1 = 1.0f / (3.0f * 3.0f * 8388608.0f);  // w=1/3, N=32*512*512
    const float C2 = 1.0f / (2.0f * 3.0f * 2097152.0f);  // w=1/2, N=32*256*256
    const float C3 = 1.0f / (3.0f * 524288.0f);          // w=1,   N=32*128*128
    float v = l1 * C1 + l2 * C2 + l3 * C3;

    // wave-64 shuffle reduction
    #pragma unroll
    for (int off = 32; off > 0; off >>= 1)
        v += __shfl_down(v, off, 64);

    __shared__ float wsum[4];
    int lane = threadIdx.x & 63;
    int wid  = threadIdx.x >> 6;
    if (lane == 0) wsum[wid] = v;
    __syncthreads();
    if (threadIdx.x == 0) {
        float s = wsum[0] + wsum[1] + wsum[2] + wsum[3];
        atomicAdd(out, s);
    }
}

extern "C" void kernel_launch(void* const* d_in, const int* in_sizes, int n_in,
                              void* d_out, int out_size, void* d_ws, size_t ws_size,
                              hipStream_t stream) {
    const float* pred = (const float*)d_in[0];
    float* out = (float*)d_out;

    // d_out is re-poisoned to 0xAA before every timed launch — zero it.
    hipMemsetAsync(out, 0, sizeof(float), stream);

    // 524288 threads / 256 = 2048 blocks
    WaveletSparsityLoss_34746285424743_kernel<<<2048, 256, 0, stream>>>(pred, out);
}

// Round 2
// 185.408 us; speedup vs baseline: 1.0089x; 1.0089x over previous
//
#include <hip/hip_runtime.h>

#define IMG_W 1024
#define IMG_H 1024
#define NBATCH 32
#define STAGE1_BLOCKS (NBATCH * (IMG_H / 8))   // 32 * 128 = 4096

// One Haar quad: a,b top row; c,d bottom row.
// Writes cA, accumulates min(|cH|,thr)+min(|cV|,thr)+min(|cD|,thr) into lsum.
__device__ __forceinline__ void haar_quad(float a, float b, float c, float d,
                                          float thr, float& cA, float& lsum) {
    float s1 = a + b, s2 = c + d;
    float d1 = a - b, d2 = c - d;
    cA = (s1 + s2) * 0.5f;
    float cH = (s1 - s2) * 0.5f;
    float cV = (d1 + d2) * 0.5f;
    float cD = (d1 - d2) * 0.5f;
    lsum += fminf(fabsf(cH), thr) + fminf(fabsf(cV), thr) + fminf(fabsf(cD), thr);
}

// Stage 1: each block handles an 8-row x 1024-col strip of one image.
// Thread tile: 8 rows x 4 cols; lane l covers cols (wid*256 + 4l .. +3), so
// every global_load_dwordx4 is 64 lanes x 16B unit-stride = 1KB contiguous.
__global__ __launch_bounds__(256)
void wavelet_stage1(const float* __restrict__ pred, float* __restrict__ partial) {
    int batch = blockIdx.x >> 7;         // / 128
    int strip = blockIdx.x & 127;
    int lane  = threadIdx.x & 63;
    int wid   = threadIdx.x >> 6;

    const float* img = pred + (size_t)batch * (IMG_W * IMG_H);
    int r0 = strip * 8;
    int c0 = wid * 256 + lane * 4;

    const float thr1 = 50.0f / 4.0f / 255.0f;   // s=1, level_idx=3
    const float thr2 = 50.0f / 2.0f / 255.0f;   // s=2, level_idx=2
    const float thr3 = 50.0f / 255.0f;          // s=3, level_idx=1

    // Issue all 8 row loads up front (independent -> MLP).
    float4 v[8];
    #pragma unroll
    for (int i = 0; i < 8; ++i) {
        v[i] = *reinterpret_cast<const float4*>(
            img + (size_t)(r0 + i) * IMG_W + c0);
    }

    float l1 = 0.0f, l2 = 0.0f, l3 = 0.0f;

    // Level 1: 4 row-pairs x 2 col-pairs -> cA1[4][2]
    float cA1[4][2];
    #pragma unroll
    for (int p = 0; p < 4; ++p) {
        float4 t = v[2 * p], b = v[2 * p + 1];
        haar_quad(t.x, t.y, b.x, b.y, thr1, cA1[p][0], l1);
        haar_quad(t.z, t.w, b.z, b.w, thr1, cA1[p][1], l1);
    }

    // Level 2: 2 row-pairs x 1 col-pair (both cols in-lane) -> cA2[2]
    float cA2[2];
    #pragma unroll
    for (int q = 0; q < 2; ++q) {
        haar_quad(cA1[2 * q][0], cA1[2 * q][1],
                  cA1[2 * q + 1][0], cA1[2 * q + 1][1], thr2, cA2[q], l2);
    }

    // Level 3: column partner lives in lane^1. Both lanes of the pair compute
    // the same quad with (a<->b, c<->d) swapped -> |cH|,|cV|,|cD| identical,
    // so fold the x2 duplication into C3 (0.5 factor). No divergence.
    float pb = __shfl_xor(cA2[0], 1, 64);
    float pd = __shfl_xor(cA2[1], 1, 64);
    float cA3;
    haar_quad(cA2[0], pb, cA2[1], pd, thr3, cA3, l3);
    (void)cA3;

    // weight_s / (3 * N_s)  (N_s = band element count, level 3 counted twice)
    const float C1 = 1.0f / (3.0f * 3.0f * 8388608.0f);
    const float C2 = 1.0f / (2.0f * 3.0f * 2097152.0f);
    const float C3 = 0.5f / (3.0f * 524288.0f);
    float s = l1 * C1 + l2 * C2 + l3 * C3;

    #pragma unroll
    for (int off = 32; off > 0; off >>= 1)
        s += __shfl_down(s, off, 64);

    __shared__ float wsum[4];
    if (lane == 0) wsum[wid] = s;
    __syncthreads();
    if (threadIdx.x == 0)
        partial[blockIdx.x] = wsum[0] + wsum[1] + wsum[2] + wsum[3];
}

// Stage 2: reduce 4096 partials -> d_out[0] (plain store; no memset needed).
__global__ __launch_bounds__(256)
void wavelet_stage2(const float* __restrict__ partial, float* __restrict__ out) {
    float s = 0.0f;
    #pragma unroll
    for (int i = 0; i < STAGE1_BLOCKS / 256; ++i)
        s += partial[threadIdx.x + i * 256];

    #pragma unroll
    for (int off = 32; off > 0; off >>= 1)
        s += __shfl_down(s, off, 64);

    __shared__ float wsum[4];
    int lane = threadIdx.x & 63;
    int wid  = threadIdx.x >> 6;
    if (lane == 0) wsum[wid] = s;
    __syncthreads();
    if (threadIdx.x == 0)
        out[0] = wsum[0] + wsum[1] + wsum[2] + wsum[3];
}

extern "C" void kernel_launch(void* const* d_in, const int* in_sizes, int n_in,
                              void* d_out, int out_size, void* d_ws, size_t ws_size,
                              hipStream_t stream) {
    const float* pred = (const float*)d_in[0];
    float* out = (float*)d_out;
    float* partial = (float*)d_ws;   // 4096 floats = 16 KB scratch

    wavelet_stage1<<<STAGE1_BLOCKS, 256, 0, stream>>>(pred, partial);
    wavelet_stage2<<<1, 256, 0, stream>>>(partial, out);
}

// Round 4
// 175.133 us; speedup vs baseline: 1.0681x; 1.0587x over previous
//
#include <hip/hip_runtime.h>

#define IMG_W 1024
#define IMG_H 1024
#define NBATCH 32
#define ROWS_PER_BLOCK 16
#define STAGE1_BLOCKS (NBATCH * (IMG_H / ROWS_PER_BLOCK))   // 32 * 64 = 2048

// Native vector type — __builtin_nontemporal_load rejects HIP_vector_type.
typedef float vfloat4 __attribute__((ext_vector_type(4)));

// One Haar quad: a,b top row; c,d bottom row.
__device__ __forceinline__ void haar_quad(float a, float b, float c, float d,
                                          float thr, float& cA, float& lsum) {
    float s1 = a + b, s2 = c + d;
    float d1 = a - b, d2 = c - d;
    cA = (s1 + s2) * 0.5f;
    float cH = (s1 - s2) * 0.5f;
    float cV = (d1 + d2) * 0.5f;
    float cD = (d1 - d2) * 0.5f;
    lsum += fminf(fabsf(cH), thr) + fminf(fabsf(cV), thr) + fminf(fabsf(cD), thr);
}

// Stage 1: each block handles a 16-row x 1024-col strip of one image.
// Thread tile: 16 rows x 4 cols; lane l at cols (wid*256 + 4l .. +3) so every
// global_load_dwordx4 is 64 lanes x 16B unit-stride = 1KB contiguous.
// 16 independent NT loads in flight per thread for HBM latency hiding.
__global__ __launch_bounds__(256)
void wavelet_stage1(const float* __restrict__ pred, float* __restrict__ partial) {
    int batch = blockIdx.x >> 6;         // / 64
    int strip = blockIdx.x & 63;
    int lane  = threadIdx.x & 63;
    int wid   = threadIdx.x >> 6;

    const float* img = pred + (size_t)batch * (IMG_W * IMG_H);
    int r0 = strip * ROWS_PER_BLOCK;
    int c0 = wid * 256 + lane * 4;

    const float thr1 = 50.0f / 4.0f / 255.0f;   // s=1, level_idx=3
    const float thr2 = 50.0f / 2.0f / 255.0f;   // s=2, level_idx=2
    const float thr3 = 50.0f / 255.0f;          // s=3, level_idx=1

    // Issue all 16 row loads up front (independent, non-temporal -> MLP).
    vfloat4 v[16];
    #pragma unroll
    for (int i = 0; i < 16; ++i) {
        v[i] = __builtin_nontemporal_load(
            reinterpret_cast<const vfloat4*>(img + (size_t)(r0 + i) * IMG_W + c0));
    }

    float l1 = 0.0f, l2 = 0.0f, l3 = 0.0f;

    // Level 1: 8 row-pairs x 2 col-pairs -> cA1[8][2]
    float cA1[8][2];
    #pragma unroll
    for (int p = 0; p < 8; ++p) {
        vfloat4 t = v[2 * p], b = v[2 * p + 1];
        haar_quad(t.x, t.y, b.x, b.y, thr1, cA1[p][0], l1);
        haar_quad(t.z, t.w, b.z, b.w, thr1, cA1[p][1], l1);
    }

    // Level 2: 4 row-pairs x 1 col-pair (in-lane) -> cA2[4]
    float cA2[4];
    #pragma unroll
    for (int q = 0; q < 4; ++q) {
        haar_quad(cA1[2 * q][0], cA1[2 * q][1],
                  cA1[2 * q + 1][0], cA1[2 * q + 1][1], thr2, cA2[q], l2);
    }

    // Level 3: column partner lives in lane^1. Both lanes of a pair compute
    // the same quad with (a<->b, c<->d) swapped -> |cH|,|cV|,|cD| identical;
    // fold the x2 duplication into C3 (0.5 factor). Two quads per lane.
    #pragma unroll
    for (int q = 0; q < 2; ++q) {
        float pb = __shfl_xor(cA2[2 * q], 1, 64);
        float pd = __shfl_xor(cA2[2 * q + 1], 1, 64);
        float cA3;
        haar_quad(cA2[2 * q], pb, cA2[2 * q + 1], pd, thr3, cA3, l3);
        (void)cA3;
    }

    // weight_s / (3 * N_s); level-3 terms duplicated x2 across the lane pair.
    const float C1 = 1.0f / (3.0f * 3.0f * 8388608.0f);
    const float C2 = 1.0f / (2.0f * 3.0f * 2097152.0f);
    const float C3 = 0.5f / (3.0f * 524288.0f);
    float s = l1 * C1 + l2 * C2 + l3 * C3;

    #pragma unroll
    for (int off = 32; off > 0; off >>= 1)
        s += __shfl_down(s, off, 64);

    __shared__ float wsum[4];
    if (lane == 0) wsum[wid] = s;
    __syncthreads();
    if (threadIdx.x == 0)
        partial[blockIdx.x] = wsum[0] + wsum[1] + wsum[2] + wsum[3];
}

// Stage 2: reduce 2048 partials -> d_out[0] (plain store; no memset needed).
__global__ __launch_bounds__(256)
void wavelet_stage2(const float* __restrict__ partial, float* __restrict__ out) {
    float s = 0.0f;
    #pragma unroll
    for (int i = 0; i < STAGE1_BLOCKS / 256; ++i)
        s += partial[threadIdx.x + i * 256];

    #pragma unroll
    for (int off = 32; off > 0; off >>= 1)
        s += __shfl_down(s, off, 64);

    __shared__ float wsum[4];
    int lane = threadIdx.x & 63;
    int wid  = threadIdx.x >> 6;
    if (lane == 0) wsum[wid] = s;
    __syncthreads();
    if (threadIdx.x == 0)
        out[0] = wsum[0] + wsum[1] + wsum[2] + wsum[3];
}

extern "C" void kernel_launch(void* const* d_in, const int* in_sizes, int n_in,
                              void* d_out, int out_size, void* d_ws, size_t ws_size,
                              hipStream_t stream) {
    const float* pred = (const float*)d_in[0];
    float* out = (float*)d_out;
    float* partial = (float*)d_ws;   // 2048 floats = 8 KB scratch

    wavelet_stage1<<<STAGE1_BLOCKS, 256, 0, stream>>>(pred, partial);
    wavelet_stage2<<<1, 256, 0, stream>>>(partial, out);
}